// Round 1
// baseline (161.268 us; speedup 1.0000x reference)
//
#include <hip/hip_runtime.h>

#define BATCH 8
#define NCLS  6
#define HW    512
#define NPIX  (BATCH * HW * HW)          // 2097152 = 2^21
#define TILE  32
#define HALO  5
#define SM    (TILE + 2 * HALO)          // 42

__device__ __forceinline__ float get4(const float4& v, int j) {
    return j == 0 ? v.x : j == 1 ? v.y : j == 2 ? v.z : v.w;
}

__global__ __launch_bounds__(256) void ls_main_kernel(
        const float* __restrict__ x,
        const int*   __restrict__ tgt,
        double*      __restrict__ acc,        // [0]=R1, [1]=R2
        unsigned long long* __restrict__ ecnt) {
    __shared__ int   s_t[SM][SM];             // halo'd target tile
    __shared__ int   s_rs[SM][TILE];          // horizontal 11-sums
    __shared__ float s_red1[4], s_red2[4];
    __shared__ int   s_rede[4];

    const int tid  = threadIdx.x;
    const int blk  = blockIdx.x;
    const int b    = blk >> 8;                // 256 tiles (16x16) per image
    const int tile = blk & 255;
    const int tr   = (tile >> 4) * TILE;
    const int tc   = (tile & 15) * TILE;

    const int* timg = tgt + b * (HW * HW);

    // ---- load 42x42 target tile with zero halo (SAME zero padding) ----
    for (int e = tid; e < SM * SM; e += 256) {
        int ly = e / SM, lx = e - ly * SM;
        int gy = tr - HALO + ly, gx = tc - HALO + lx;
        int v = 0;
        if (gy >= 0 && gy < HW && gx >= 0 && gx < HW) v = timg[gy * HW + gx];
        s_t[ly][lx] = v;
    }
    __syncthreads();

    // ---- horizontal 11-wide sums: s_rs[ry][cx] over s_t[ry][cx..cx+10] ----
    for (int e = tid; e < SM * TILE; e += 256) {
        int ry = e >> 5, cx = e & 31;
        int s = 0;
#pragma unroll
        for (int dx = 0; dx <= 2 * HALO; dx++) s += s_t[ry][cx + dx];
        s_rs[ry][cx] = s;
    }
    __syncthreads();

    // ---- each thread: 4 consecutive pixels (float4-friendly) ----
    const int p0 = tid * 4;
    const int py = p0 >> 5;                   // tid / 8
    const int px = p0 & 31;                   // 4 * (tid % 8)

    int4 bs = make_int4(0, 0, 0, 0);
#pragma unroll
    for (int dy = 0; dy <= 2 * HALO; dy++) {
        const int4 r = *(const int4*)&s_rs[py + dy][px];
        bs.x += r.x; bs.y += r.y; bs.z += r.z; bs.w += r.w;
    }
    const int bsa[4] = {bs.x, bs.y, bs.z, bs.w};
    int t4[4];
#pragma unroll
    for (int j = 0; j < 4; j++) t4[j] = s_t[py + HALO][px + HALO + j];

    const int gy = tr + py;
    const int gx = tc + px;
    const float* xb = x + (size_t)b * NCLS * (HW * HW) + (size_t)gy * HW + gx;

    float4 xc[NCLS];
#pragma unroll
    for (int ch = 0; ch < NCLS; ch++)
        xc[ch] = *(const float4*)(xb + (size_t)ch * (HW * HW));

    float r1 = 0.f, r2 = 0.f;
    int ec = 0;
#pragma unroll
    for (int j = 0; j < 4; j++) {
        const float a0 = get4(xc[0], j), a1 = get4(xc[1], j), a2 = get4(xc[2], j);
        const float a3 = get4(xc[3], j), a4 = get4(xc[4], j), a5 = get4(xc[5], j);
        const float m  = fmaxf(fmaxf(fmaxf(a0, a1), fmaxf(a2, a3)), fmaxf(a4, a5));
        const float se = __expf(a0 - m) + __expf(a1 - m) + __expf(a2 - m) +
                         __expf(a3 - m) + __expf(a4 - m) + __expf(a5 - m);
        const float lse = m + __logf(se);
        const int   t   = t4[j];
        const float xt  = t == 0 ? a0 : t == 1 ? a1 : t == 2 ? a2 :
                          t == 3 ? a3 : t == 4 ? a4 : a5;
        const float lpl = xt - lse;
        r1 += lpl;
        const int ev = 121 * t - bsa[j];      // exact integer edge test
        if (ev != 0) {
            const float S = (a0 + a1 + a2 + a3 + a4 + a5) - 6.f * lse;
            r2 += S - (11.0f / 6.0f) * lpl;
            ec++;
        }
    }

    // ---- block reduction: wave64 shuffle, then cross-wave via LDS ----
#pragma unroll
    for (int off = 32; off > 0; off >>= 1) {
        r1 += __shfl_down(r1, off);
        r2 += __shfl_down(r2, off);
        ec += __shfl_down(ec, off);
    }
    const int wave = tid >> 6;
    if ((tid & 63) == 0) { s_red1[wave] = r1; s_red2[wave] = r2; s_rede[wave] = ec; }
    __syncthreads();
    if (tid == 0) {
        float R1 = 0.f, R2 = 0.f; int E = 0;
#pragma unroll
        for (int w = 0; w < 4; w++) { R1 += s_red1[w]; R2 += s_red2[w]; E += s_rede[w]; }
        atomicAdd(&acc[0], (double)R1);
        atomicAdd(&acc[1], (double)R2);
        atomicAdd(ecnt, (unsigned long long)E);
    }
}

__global__ void ls_finalize_kernel(const double* __restrict__ acc,
                                   const unsigned long long* __restrict__ ecnt,
                                   float* __restrict__ out) {
    const double r1 = acc[0];
    const double r2 = acc[1];
    // (float)E / 2^21 is exact (E < 2^24), matching the f32 reference's s
    const float s = fminf((float)(*ecnt) * (1.0f / (float)NPIX), 0.2f);
    const double loss = (r1 + (double)s * r2) * (1.0 / (double)NPIX);
    out[0] = (float)(-loss);
}

extern "C" void kernel_launch(void* const* d_in, const int* in_sizes, int n_in,
                              void* d_out, int out_size, void* d_ws, size_t ws_size,
                              hipStream_t stream) {
    const float* x   = (const float*)d_in[0];
    const int*   tgt = (const int*)d_in[1];
    float*       out = (float*)d_out;

    double* acc = (double*)d_ws;
    unsigned long long* ecnt = (unsigned long long*)((char*)d_ws + 16);

    hipMemsetAsync(d_ws, 0, 32, stream);
    ls_main_kernel<<<BATCH * 256, 256, 0, stream>>>(x, tgt, acc, ecnt);
    ls_finalize_kernel<<<1, 1, 0, stream>>>(acc, ecnt, out);
}

// Round 2
// 124.936 us; speedup vs baseline: 1.2908x; 1.2908x over previous
//
#include <hip/hip_runtime.h>

#define BATCH   8
#define NCLS    6
#define HW      512
#define IMGPIX  (HW * HW)                 // 262144 = 2^18
#define NPIX    (BATCH * IMGPIX)          // 2097152 = 2^21
#define NQUAD   (NPIX / 4)                // 524288 packed u32s
#define TILE    32
#define HALO    5
#define SM      (TILE + 2 * HALO)         // 42
#define RSTRIDE 36                        // padded row stride: kills 8-way bank conflict

#define NB2     1024                      // main-kernel blocks
#define QPT     2                         // quads per thread (NB2*256*QPT*4 == NPIX)

__device__ __forceinline__ float get4(const float4& v, int j) {
    return j == 0 ? v.x : j == 1 ? v.y : j == 2 ? v.z : v.w;
}

// ---------------------------------------------------------------------------
// K1: target -> packed (target | edge<<3) byte per pixel, 4 pixels per u32.
// Also zeroes the K2 finalize counter (stream-ordered before K2).
// ---------------------------------------------------------------------------
__global__ __launch_bounds__(256) void edge_pack_kernel(
        const int* __restrict__ tgt,
        unsigned int* __restrict__ pack,
        unsigned int* __restrict__ counter) {
    if (blockIdx.x == 0 && threadIdx.x == 0) *counter = 0u;

    __shared__ int s_t[SM][SM];           // halo'd target tile
    __shared__ int s_rs[SM][RSTRIDE];     // horizontal 11-sums (padded stride)

    const int tid  = threadIdx.x;
    const int blk  = blockIdx.x;
    const int b    = blk >> 8;            // 256 tiles (16x16) per image
    const int tile = blk & 255;
    const int tr   = (tile >> 4) * TILE;
    const int tc   = (tile & 15) * TILE;

    const int* timg = tgt + b * IMGPIX;

    // 42x42 halo'd load, zero padding (SAME conv semantics)
    for (int e = tid; e < SM * SM; e += 256) {
        int ly = e / SM, lx = e - ly * SM;
        int gy = tr - HALO + ly, gx = tc - HALO + lx;
        int v = 0;
        if (gy >= 0 && gy < HW && gx >= 0 && gx < HW) v = timg[gy * HW + gx];
        s_t[ly][lx] = v;
    }
    __syncthreads();

    // horizontal 11-wide sums
    for (int e = tid; e < SM * TILE; e += 256) {
        int ry = e >> 5, cx = e & 31;
        int s = 0;
#pragma unroll
        for (int dx = 0; dx <= 2 * HALO; dx++) s += s_t[ry][cx + dx];
        s_rs[ry][cx] = s;
    }
    __syncthreads();

    // each thread: one quad of 4 consecutive pixels
    const int p0 = tid * 4;
    const int py = p0 >> 5;               // tid / 8
    const int px = p0 & 31;               // 4 * (tid % 8)

    int4 bs = make_int4(0, 0, 0, 0);
#pragma unroll
    for (int dy = 0; dy <= 2 * HALO; dy++) {
        const int4 r = *(const int4*)&s_rs[py + dy][px];
        bs.x += r.x; bs.y += r.y; bs.z += r.z; bs.w += r.w;
    }
    const int bsa[4] = {bs.x, bs.y, bs.z, bs.w};

    unsigned int pk = 0;
#pragma unroll
    for (int j = 0; j < 4; j++) {
        const int t  = s_t[py + HALO][px + HALO + j];
        const int ev = 121 * t - bsa[j];  // exact integer edge test
        const unsigned int byte = (unsigned int)t | ((ev != 0) ? 8u : 0u);
        pk |= byte << (8 * j);
    }

    const int gy = tr + py;
    const int gx = tc + px;
    pack[(b << 16) + (gy << 7) + (gx >> 2)] = pk;
}

// ---------------------------------------------------------------------------
// K2: barrier-free stream over x; per-block partials; last block finalizes.
// ---------------------------------------------------------------------------
__global__ __launch_bounds__(256) void ls_main_kernel(
        const float* __restrict__ x,
        const unsigned int* __restrict__ pack,
        float* __restrict__ part,          // [0..NB2)=R1, [NB2..2NB2)=R2, [2NB2..3NB2)=E
        unsigned int* __restrict__ counter,
        float* __restrict__ out) {
    const int tid = threadIdx.x;
    const int bid = blockIdx.x;
    const int g0  = bid * 256 + tid;      // quad index, stride NB2*256 per pass

    // ---- issue all loads up front (MLP) ----
    unsigned int pk[QPT];
    float4 xc[QPT][NCLS];
#pragma unroll
    for (int k = 0; k < QPT; k++) {
        const int g  = g0 + k * (NB2 * 256);
        pk[k] = pack[g];
        const int p  = g << 2;
        const int b  = p >> 18;
        const int qi = p & (IMGPIX - 1);
        const float* xb = x + ((size_t)(b * NCLS) << 18) + qi;
#pragma unroll
        for (int c = 0; c < NCLS; c++)
            xc[k][c] = *(const float4*)(xb + ((size_t)c << 18));
    }

    float r1 = 0.f, r2 = 0.f;
    int ec = 0;
#pragma unroll
    for (int k = 0; k < QPT; k++) {
#pragma unroll
        for (int j = 0; j < 4; j++) {
            const float a0 = get4(xc[k][0], j), a1 = get4(xc[k][1], j);
            const float a2 = get4(xc[k][2], j), a3 = get4(xc[k][3], j);
            const float a4 = get4(xc[k][4], j), a5 = get4(xc[k][5], j);
            const float m  = fmaxf(fmaxf(fmaxf(a0, a1), fmaxf(a2, a3)), fmaxf(a4, a5));
            const float se = __expf(a0 - m) + __expf(a1 - m) + __expf(a2 - m) +
                             __expf(a3 - m) + __expf(a4 - m) + __expf(a5 - m);
            const float lse = m + __logf(se);
            const int   t   = (pk[k] >> (8 * j)) & 7;
            const int   eb  = (pk[k] >> (8 * j + 3)) & 1;
            const float xt  = t == 0 ? a0 : t == 1 ? a1 : t == 2 ? a2 :
                              t == 3 ? a3 : t == 4 ? a4 : a5;
            const float lpl = xt - lse;
            r1 += lpl;
            const float S = (a0 + a1 + a2 + a3 + a4 + a5) - 6.f * lse;
            r2 = fmaf((float)eb, S - (11.0f / 6.0f) * lpl, r2);
            ec += eb;
        }
    }

    // ---- block reduction ----
    __shared__ float sw1[4], sw2[4];
    __shared__ int   swe[4];
    __shared__ bool  islast;
#pragma unroll
    for (int off = 32; off > 0; off >>= 1) {
        r1 += __shfl_down(r1, off);
        r2 += __shfl_down(r2, off);
        ec += __shfl_down(ec, off);
    }
    const int wave = tid >> 6;
    if ((tid & 63) == 0) { sw1[wave] = r1; sw2[wave] = r2; swe[wave] = ec; }
    __syncthreads();

    if (tid == 0) {
        const float R1 = sw1[0] + sw1[1] + sw1[2] + sw1[3];
        const float R2 = sw2[0] + sw2[1] + sw2[2] + sw2[3];
        const int   E  = swe[0] + swe[1] + swe[2] + swe[3];
        __hip_atomic_store(&part[bid],           R1,      __ATOMIC_RELAXED, __HIP_MEMORY_SCOPE_AGENT);
        __hip_atomic_store(&part[NB2 + bid],     R2,      __ATOMIC_RELAXED, __HIP_MEMORY_SCOPE_AGENT);
        __hip_atomic_store(&part[2 * NB2 + bid], (float)E,__ATOMIC_RELAXED, __HIP_MEMORY_SCOPE_AGENT);
        const unsigned prev = __hip_atomic_fetch_add(counter, 1u,
                                  __ATOMIC_ACQ_REL, __HIP_MEMORY_SCOPE_AGENT);
        islast = (prev == NB2 - 1);
    }
    __syncthreads();

    // ---- last block: final reduction + scalar epilogue ----
    if (islast) {
        double d1 = 0.0, d2 = 0.0, de = 0.0;
        for (int i = tid; i < NB2; i += 256) {
            d1 += (double)__hip_atomic_load(&part[i],           __ATOMIC_RELAXED, __HIP_MEMORY_SCOPE_AGENT);
            d2 += (double)__hip_atomic_load(&part[NB2 + i],     __ATOMIC_RELAXED, __HIP_MEMORY_SCOPE_AGENT);
            de += (double)__hip_atomic_load(&part[2 * NB2 + i], __ATOMIC_RELAXED, __HIP_MEMORY_SCOPE_AGENT);
        }
#pragma unroll
        for (int off = 32; off > 0; off >>= 1) {
            d1 += __shfl_down(d1, off);
            d2 += __shfl_down(d2, off);
            de += __shfl_down(de, off);
        }
        __shared__ double sd1[4], sd2[4], sde[4];
        if ((tid & 63) == 0) { sd1[wave] = d1; sd2[wave] = d2; sde[wave] = de; }
        __syncthreads();
        if (tid == 0) {
            const double R1 = sd1[0] + sd1[1] + sd1[2] + sd1[3];
            const double R2 = sd2[0] + sd2[1] + sd2[2] + sd2[3];
            const double E  = sde[0] + sde[1] + sde[2] + sde[3];
            // (float)E / 2^21 exact (E < 2^24) -> matches f32 reference s
            const float  s  = fminf((float)E * (1.0f / (float)NPIX), 0.2f);
            const double loss = (R1 + (double)s * R2) * (1.0 / (double)NPIX);
            out[0] = (float)(-loss);
        }
    }
}

extern "C" void kernel_launch(void* const* d_in, const int* in_sizes, int n_in,
                              void* d_out, int out_size, void* d_ws, size_t ws_size,
                              hipStream_t stream) {
    const float* x   = (const float*)d_in[0];
    const int*   tgt = (const int*)d_in[1];
    float*       out = (float*)d_out;

    // ws layout: [0, 2MB) pack; then 3*NB2 float partials; then u32 counter
    unsigned int* pack    = (unsigned int*)d_ws;
    float*        part    = (float*)((char*)d_ws + (size_t)NQUAD * 4);
    unsigned int* counter = (unsigned int*)((char*)d_ws + (size_t)NQUAD * 4 + 3 * NB2 * 4);

    edge_pack_kernel<<<BATCH * 256, 256, 0, stream>>>(tgt, pack, counter);
    ls_main_kernel<<<NB2, 256, 0, stream>>>(x, pack, part, counter, out);
}